// Round 2
// baseline (320.547 us; speedup 1.0000x reference)
//
#include <hip/hip_runtime.h>
#include <cstdint>
#include <cstddef>

#define S_LEN 4096
#define HIDD 768
#define NH 12
#define FFD 3072

typedef float f32x4 __attribute__((ext_vector_type(4)));
typedef short s16x8 __attribute__((ext_vector_type(8)));
typedef short s16x4 __attribute__((ext_vector_type(4)));

__device__ __forceinline__ short f2bf(float f) {
  unsigned u = __float_as_uint(f);
  u += 0x7fffu + ((u >> 16) & 1u);
  return (short)(u >> 16);
}
__device__ __forceinline__ float bf2f(short s) {
  return __uint_as_float(((unsigned)(unsigned short)s) << 16);
}

// async global->LDS, 16B per lane; LDS dest must be wave-uniform (HW writes
// lane i at ldsbase + i*16)
__device__ __forceinline__ void gload16(const short* g, short* l) {
  __builtin_amdgcn_global_load_lds(
      (__attribute__((address_space(1))) void*)(void*)const_cast<short*>(g),
      (__attribute__((address_space(3))) void*)l, 16, 0, 0);
}

// ---------------- conversion: f32 -> bf16 (flat, vectorized) ----------------
__global__ void convx_k(const float* __restrict__ x, short* __restrict__ o) {
  size_t i = (size_t)blockIdx.x * 256 + threadIdx.x;
  float4 f = ((const float4*)x)[i];
  s16x4 v;
  v[0] = f2bf(f.x); v[1] = f2bf(f.y); v[2] = f2bf(f.z); v[3] = f2bf(f.w);
  ((s16x4*)o)[i] = v;
}

// ------------- weight transpose + convert: W[R][C] f32 -> Wt[C][R] bf16 -----
__global__ void wtrans_k(const float* __restrict__ Wq, const float* __restrict__ Wk,
                         const float* __restrict__ Wv, const float* __restrict__ Wd,
                         const float* __restrict__ Wf, const float* __restrict__ Wo,
                         short* __restrict__ oq, short* __restrict__ ok_,
                         short* __restrict__ ov, short* __restrict__ od,
                         short* __restrict__ of_, short* __restrict__ oo) {
  __shared__ float tl[64][65];
  int id = blockIdx.x;
  const float* in; short* out; int R, C, tr, tc;
  if (id < 576) {
    int wsel = id / 144; int t = id % 144; tr = t / 12; tc = t % 12; R = 768; C = 768;
    in = wsel == 0 ? Wq : wsel == 1 ? Wk : wsel == 2 ? Wv : Wd;
    out = wsel == 0 ? oq : wsel == 1 ? ok_ : wsel == 2 ? ov : od;
  } else if (id < 1152) {
    int t = id - 576; tr = t / 48; tc = t % 48; R = 768; C = 3072; in = Wf; out = of_;
  } else {
    int t = id - 1152; tr = t / 12; tc = t % 12; R = 3072; C = 768; in = Wo; out = oo;
  }
  int r0 = tr * 64, c0 = tc * 64;
  int tid = threadIdx.x;
  #pragma unroll
  for (int i = 0; i < 16; i++) {
    int idx = i * 256 + tid; int r = idx >> 6, cc = idx & 63;
    tl[r][cc] = in[(size_t)(r0 + r) * C + c0 + cc];
  }
  __syncthreads();
  #pragma unroll
  for (int i = 0; i < 16; i++) {
    int idx = i * 256 + tid; int cc = idx >> 6, rr = idx & 63;
    out[(size_t)(c0 + cc) * R + r0 + rr] = f2bf(tl[rr][cc]);
  }
}

// ---------------- v head-layout transpose: [bh][s][64] -> [bh][64][s] -------
__global__ void vtrans_k(const short* __restrict__ vh, short* __restrict__ vth) {
  __shared__ short tl[64][72];
  int s0 = blockIdx.x * 64; int bh = blockIdx.y;
  int tid = threadIdx.x;
  const short* base = vh + ((size_t)bh << 18);
  #pragma unroll
  for (int i = 0; i < 16; i++) {
    int idx = i * 256 + tid; int r = idx >> 6, cc = idx & 63;
    tl[r][cc] = base[(size_t)(s0 + r) * 64 + cc];
  }
  __syncthreads();
  short* ob = vth + ((size_t)bh << 18);
  #pragma unroll
  for (int i = 0; i < 16; i++) {
    int idx = i * 256 + tid; int dh = idx >> 6, s = idx & 63;
    ob[((size_t)dh << 12) + s0 + s] = tl[s][dh];
  }
}

// ---------------- generic bf16 GEMM: C[M][N] = A[M][K] * Bt[N][K]^T ---------
// m97 structure: linear LDS [128][64], global_load_lds width=16 staging.
// EPI 0: fused QKV, N=2304: per-col {q,k,v} select, (acc+bias)*scale,
//        head-split bf16 -> outbase + which*B*S*HID + [((b*NH+h)*S+s)*64+dh]
// EPI 1: exact GELU(acc+bias) -> bf16 row-major
// EPI 2: acc+bias+resid_f32   -> f32 row-major
// EPI 3: acc+bias+resid_bf16  -> f32 row-major
template <int EPI>
__global__ void __launch_bounds__(256) gemm_bt(
    const short* __restrict__ A, const short* __restrict__ Bt,
    const float* __restrict__ bias, const float* __restrict__ bias1,
    const float* __restrict__ bias2, const void* __restrict__ resid,
    void* __restrict__ out, int N, int K) {
  __shared__ __align__(16) short As[128 * 64];
  __shared__ __align__(16) short Bs[128 * 64];
  const int tid = threadIdx.x;
  const int lane = tid & 63;
  const int w = tid >> 6;
  const int wr = w >> 1, wc = w & 1;
  const int m0 = blockIdx.x * 128, n0 = blockIdx.y * 128;
  const int lr = lane >> 3, seg = lane & 7;   // staging: row-in-chunk, 16B segment
  f32x4 acc[4][4];
  #pragma unroll
  for (int i = 0; i < 4; i++)
    #pragma unroll
    for (int j = 0; j < 4; j++) { acc[i][j][0] = 0.f; acc[i][j][1] = 0.f; acc[i][j][2] = 0.f; acc[i][j][3] = 0.f; }

  const short* Ab = A + (size_t)(m0 + lr) * K + seg * 8;
  const short* Bb = Bt + (size_t)(n0 + lr) * K + seg * 8;
  for (int k0 = 0; k0 < K; k0 += 64) {
    #pragma unroll
    for (int i = 0; i < 4; i++) {
      const int ca = w * 4 + i;                     // chunk 0..15, 8 rows each
      gload16(Ab + (size_t)(ca * 8) * K + k0, &As[ca * 512]);
      gload16(Bb + (size_t)(ca * 8) * K + k0, &Bs[ca * 512]);
    }
    __syncthreads();   // drains vmcnt(0) before barrier
    const int kc = (lane >> 4) * 8;
    #pragma unroll
    for (int ks = 0; ks < 2; ks++) {
      s16x8 af[4], bfr[4];
      #pragma unroll
      for (int mt = 0; mt < 4; mt++)
        af[mt] = *(const s16x8*)&As[(wr * 64 + mt * 16 + (lane & 15)) * 64 + ks * 32 + kc];
      #pragma unroll
      for (int nt = 0; nt < 4; nt++)
        bfr[nt] = *(const s16x8*)&Bs[(wc * 64 + nt * 16 + (lane & 15)) * 64 + ks * 32 + kc];
      #pragma unroll
      for (int mt = 0; mt < 4; mt++)
        #pragma unroll
        for (int nt = 0; nt < 4; nt++)
          acc[mt][nt] = __builtin_amdgcn_mfma_f32_16x16x32_bf16(af[mt], bfr[nt], acc[mt][nt], 0, 0, 0);
    }
    __syncthreads();
  }
  #pragma unroll
  for (int nt = 0; nt < 4; nt++) {
    const int col = n0 + wc * 64 + nt * 16 + (lane & 15);
    if (EPI == 0) {
      const int cwhich = col >= 1536 ? 2 : (col >= 768 ? 1 : 0);
      const int cwi = col - cwhich * 768;
      const float* bsel = cwhich == 0 ? bias : (cwhich == 1 ? bias1 : bias2);
      const float bvv = bsel[cwi];
      const float sc = (cwhich == 0) ? 0.125f : 1.f;
      const int hh = cwi >> 6, dh = cwi & 63;
      short* outp = (short*)out + (size_t)cwhich * ((size_t)8192 * 768);
      #pragma unroll
      for (int mt = 0; mt < 4; mt++) {
        #pragma unroll
        for (int r = 0; r < 4; r++) {
          const int row = m0 + wr * 64 + mt * 16 + (lane >> 4) * 4 + r;
          const int b = row >> 12, s = row & 4095;
          outp[((((size_t)b * NH + hh) * S_LEN + s) << 6) + dh] = f2bf((acc[mt][nt][r] + bvv) * sc);
        }
      }
    } else {
      const float bvv = bias[col];
      #pragma unroll
      for (int mt = 0; mt < 4; mt++) {
        #pragma unroll
        for (int r = 0; r < 4; r++) {
          const int row = m0 + wr * 64 + mt * 16 + (lane >> 4) * 4 + r;
          float v = acc[mt][nt][r] + bvv;
          if (EPI == 1) {
            float g = 0.5f * v * (1.f + erff(v * 0.70710678118f));
            ((short*)out)[(size_t)row * N + col] = f2bf(g);
          } else if (EPI == 2) {
            ((float*)out)[(size_t)row * N + col] = v + ((const float*)resid)[(size_t)row * N + col];
          } else {
            ((float*)out)[(size_t)row * N + col] = v + bf2f(((const short*)resid)[(size_t)row * N + col]);
          }
        }
      }
    }
  }
}

// ---------------- banded attention, one block per (chunk, b*h) --------------
// LDS: Kb [384][72] bf16 (phase 1) overlaid by Vt [64][392] (phase 2),
//      dmw [384] f32, Pb 8 waves x [16][392] bf16.   total 157,184 B
__global__ void __launch_bounds__(512, 1) attn_k(
    const short* __restrict__ qh, const short* __restrict__ kh,
    const short* __restrict__ vth, const int* __restrict__ am,
    short* __restrict__ ctx) {
  extern __shared__ char smraw[];
  short* Kb = (short*)smraw;
  float* dmw = (float*)(smraw + 55296);
  short* Pb = (short*)(smraw + 56832);
  const int c = blockIdx.x;
  const int bh = blockIdx.y;
  const int b = bh / NH, hh = bh % NH;
  const int tid = threadIdx.x, lane = tid & 63, w = tid >> 6;
  const int q0 = c * 128, kw0 = q0 - 128;

  // stage K window (clamped; invalid positions masked later)
  for (int ch = tid; ch < 3072; ch += 512) {
    int n = ch >> 3, seg = ch & 7;
    int kp = kw0 + n; kp = kp < 0 ? 0 : (kp > S_LEN - 1 ? S_LEN - 1 : kp);
    *(s16x8*)&Kb[n * 72 + seg * 8] = *(const s16x8*)&kh[(((size_t)bh * S_LEN + kp) << 6) + seg * 8];
  }
  for (int n = tid; n < 384; n += 512) {
    int kp = kw0 + n;
    float d;
    if (kp < 0 || kp >= S_LEN) d = -1e30f;
    else d = (am[b * S_LEN + kp] != 0) ? -10000.f : 0.f;
    dmw[n] = d;
  }
  __syncthreads();

  // Q fragments (direct from global, q pre-scaled by 1/8)
  const short* qrow = qh + ((((size_t)bh * S_LEN) + q0 + w * 16 + (lane & 15)) << 6);
  s16x8 aq0 = *(const s16x8*)&qrow[(lane >> 4) * 8];
  s16x8 aq1 = *(const s16x8*)&qrow[32 + (lane >> 4) * 8];

  f32x4 sacc[24];
  #pragma unroll
  for (int t = 0; t < 24; t++) { sacc[t][0] = 0.f; sacc[t][1] = 0.f; sacc[t][2] = 0.f; sacc[t][3] = 0.f; }
  #pragma unroll
  for (int t = 0; t < 24; t++) {
    const short* kr = &Kb[(t * 16 + (lane & 15)) * 72 + (lane >> 4) * 8];
    s16x8 bk0 = *(const s16x8*)&kr[0];
    s16x8 bk1 = *(const s16x8*)&kr[32];
    sacc[t] = __builtin_amdgcn_mfma_f32_16x16x32_bf16(aq0, bk0, sacc[t], 0, 0, 0);
    sacc[t] = __builtin_amdgcn_mfma_f32_16x16x32_bf16(aq1, bk1, sacc[t], 0, 0, 0);
  }
  // masks (band + position/attention mask)
  const int mbase = w * 16 + (lane >> 4) * 4;
  #pragma unroll
  for (int t = 0; t < 24; t++) {
    int n = t * 16 + (lane & 15);
    float d = dmw[n];
    #pragma unroll
    for (int r = 0; r < 4; r++) {
      int j = n - (mbase + r);
      float sv = sacc[t][r] + d;
      if (j < 0 || j > 256) sv = -1e30f;
      sacc[t][r] = sv;
    }
  }
  // softmax (rows spread over 16-lane groups) + P -> LDS bf16
  short* Pw = Pb + w * 16 * 392;
  #pragma unroll
  for (int r = 0; r < 4; r++) {
    float mx = -3e38f;
    #pragma unroll
    for (int t = 0; t < 24; t++) mx = fmaxf(mx, sacc[t][r]);
    #pragma unroll
    for (int d = 1; d < 16; d <<= 1) mx = fmaxf(mx, __shfl_xor(mx, d));
    float sum = 0.f;
    #pragma unroll
    for (int t = 0; t < 24; t++) { float p = __expf(sacc[t][r] - mx); sacc[t][r] = p; sum += p; }
    #pragma unroll
    for (int d = 1; d < 16; d <<= 1) sum += __shfl_xor(sum, d);
    float inv = 1.f / sum;
    #pragma unroll
    for (int t = 0; t < 24; t++)
      Pw[((lane >> 4) * 4 + r) * 392 + t * 16 + (lane & 15)] = f2bf(sacc[t][r] * inv);
  }
  __syncthreads();  // everyone done reading Kb

  // stage Vt (overlay Kb): Vt[dh][n] = v^T, rows contiguous in n
  short* Vt = (short*)smraw;
  for (int ch = tid; ch < 3072; ch += 512) {
    int dh = ch / 48, seg = ch % 48;
    int n0 = seg * 8, kp0 = kw0 + n0;
    const short* vr = vth + (((size_t)bh * 64 + dh) << 12);
    s16x8 vv;
    if (kp0 >= 0 && kp0 + 7 < S_LEN) {
      vv = *(const s16x8*)&vr[kp0];
    } else {
      #pragma unroll
      for (int e = 0; e < 8; e++) {
        int kp = kp0 + e; kp = kp < 0 ? 0 : (kp > S_LEN - 1 ? S_LEN - 1 : kp);
        vv[e] = vr[kp];
      }
    }
    *(s16x8*)&Vt[dh * 392 + n0] = vv;
  }
  __syncthreads();

  // PV: C2[16][64] per wave
  f32x4 oacc[4];
  #pragma unroll
  for (int i = 0; i < 4; i++) { oacc[i][0] = 0.f; oacc[i][1] = 0.f; oacc[i][2] = 0.f; oacc[i][3] = 0.f; }
  #pragma unroll
  for (int ksp = 0; ksp < 12; ksp++) {
    s16x8 pa = *(const s16x8*)&Pw[(lane & 15) * 392 + ksp * 32 + (lane >> 4) * 8];
    #pragma unroll
    for (int ct = 0; ct < 4; ct++) {
      s16x8 vb = *(const s16x8*)&Vt[(ct * 16 + (lane & 15)) * 392 + ksp * 32 + (lane >> 4) * 8];
      oacc[ct] = __builtin_amdgcn_mfma_f32_16x16x32_bf16(pa, vb, oacc[ct], 0, 0, 0);
    }
  }
  // write ctx as [B][S][H*64] bf16
  #pragma unroll
  for (int ct = 0; ct < 4; ct++) {
    #pragma unroll
    for (int r = 0; r < 4; r++) {
      int srow = q0 + w * 16 + (lane >> 4) * 4 + r;
      int col = hh * 64 + ct * 16 + (lane & 15);
      ctx[((size_t)b * S_LEN + srow) * HIDD + col] = f2bf(oacc[ct][r]);
    }
  }
}

// ---------------- LayerNorm, one wave per row (HID=768) ---------------------
template <int OUTBF>
__global__ void ln_k(const float* __restrict__ in, const float* __restrict__ g,
                     const float* __restrict__ bb, void* __restrict__ out) {
  int row = blockIdx.x * 4 + (threadIdx.x >> 6);
  int lane = threadIdx.x & 63;
  const float4* x = (const float4*)(in + (size_t)row * HIDD);
  float4 v0 = x[lane], v1 = x[lane + 64], v2 = x[lane + 128];
  float s = v0.x + v0.y + v0.z + v0.w + v1.x + v1.y + v1.z + v1.w + v2.x + v2.y + v2.z + v2.w;
  float ss = v0.x * v0.x + v0.y * v0.y + v0.z * v0.z + v0.w * v0.w
           + v1.x * v1.x + v1.y * v1.y + v1.z * v1.z + v1.w * v1.w
           + v2.x * v2.x + v2.y * v2.y + v2.z * v2.z + v2.w * v2.w;
  #pragma unroll
  for (int d = 1; d < 64; d <<= 1) { s += __shfl_xor(s, d); ss += __shfl_xor(ss, d); }
  float mean = s * (1.f / 768.f);
  float var = ss * (1.f / 768.f) - mean * mean;
  float rs = rsqrtf(var + 1e-12f);
  const float4* gp = (const float4*)g;
  const float4* bp = (const float4*)bb;
  #pragma unroll
  for (int seg = 0; seg < 3; seg++) {
    int idx = lane + seg * 64;
    float4 vv = seg == 0 ? v0 : seg == 1 ? v1 : v2;
    float4 gg = gp[idx], b4 = bp[idx];
    float o0 = (vv.x - mean) * rs * gg.x + b4.x;
    float o1 = (vv.y - mean) * rs * gg.y + b4.y;
    float o2 = (vv.z - mean) * rs * gg.z + b4.z;
    float o3 = (vv.w - mean) * rs * gg.w + b4.w;
    if (OUTBF) {
      s16x4 o; o[0] = f2bf(o0); o[1] = f2bf(o1); o[2] = f2bf(o2); o[3] = f2bf(o3);
      ((s16x4*)out)[(size_t)row * 192 + idx] = o;
    } else {
      float4 o; o.x = o0; o.y = o1; o.z = o2; o.w = o3;
      ((float4*)out)[(size_t)row * 192 + idx] = o;
    }
  }
}

extern "C" void kernel_launch(void* const* d_in, const int* in_sizes, int n_in,
                              void* d_out, int out_size, void* d_ws, size_t ws_size,
                              hipStream_t stream) {
  const float* hid = (const float*)d_in[0];
  const int* am = (const int*)d_in[1];
  const float* Wq = (const float*)d_in[2];  const float* bq = (const float*)d_in[3];
  const float* Wk = (const float*)d_in[4];  const float* bk = (const float*)d_in[5];
  const float* Wv = (const float*)d_in[6];  const float* bv = (const float*)d_in[7];
  const float* Wd = (const float*)d_in[8];  const float* bd = (const float*)d_in[9];
  const float* g1 = (const float*)d_in[10]; const float* b1 = (const float*)d_in[11];
  const float* Wf = (const float*)d_in[12]; const float* bf = (const float*)d_in[13];
  const float* Wo = (const float*)d_in[14]; const float* bo = (const float*)d_in[15];
  const float* g2 = (const float*)d_in[16]; const float* b2 = (const float*)d_in[17];

  char* ws = (char*)d_ws;
  size_t off = 0;
  auto alloc = [&](size_t bytes) { char* p = ws + off; off += (bytes + 255) & ~(size_t)255; return p; };
  short* Xb   = (short*)alloc((size_t)8192 * 768 * 2);
  // NOTE: Wqb/Wkb/Wvb must stay contiguous (fused QKV GEMM reads them as one
  // [2304][768] Bt). Each is 768*768*2 bytes (256-aligned), so no gaps.
  short* Wqb  = (short*)alloc((size_t)768 * 768 * 2);
  short* Wkb  = (short*)alloc((size_t)768 * 768 * 2);
  short* Wvb  = (short*)alloc((size_t)768 * 768 * 2);
  short* Wdb  = (short*)alloc((size_t)768 * 768 * 2);
  short* Wfb  = (short*)alloc((size_t)3072 * 768 * 2);
  short* Wob  = (short*)alloc((size_t)768 * 3072 * 2);
  // qh/kh/vh contiguous (fused QKV epilogue indexes qh + which*8192*768)
  short* qh   = (short*)alloc((size_t)8192 * 768 * 2);
  short* kh   = (short*)alloc((size_t)8192 * 768 * 2);
  short* vh   = (short*)alloc((size_t)8192 * 768 * 2);
  short* vth  = (short*)alloc((size_t)8192 * 768 * 2);
  short* ctx  = (short*)alloc((size_t)8192 * 768 * 2);
  short* aob  = (short*)alloc((size_t)8192 * 768 * 2);   // attn_out bf16
  short* ffb  = (short*)alloc((size_t)8192 * 3072 * 2);
  float* f2r  = (float*)alloc((size_t)8192 * 768 * 4);   // ff2 + resid f32
  float* ln1in = (float*)d_out;                          // d_out as f32 scratch
  (void)vh; (void)kh;

  hipFuncSetAttribute(reinterpret_cast<const void*>(attn_k),
                      hipFuncAttributeMaxDynamicSharedMemorySize, 157184);

  convx_k<<<6144, 256, 0, stream>>>(hid, Xb);
  wtrans_k<<<1728, 256, 0, stream>>>(Wq, Wk, Wv, Wd, Wf, Wo, Wqb, Wkb, Wvb, Wdb, Wfb, Wob);

  // fused QKV: C[8192][2304] = Xb * [Wqb;Wkb;Wvb]^T, head-split epilogue
  gemm_bt<0><<<dim3(64, 18), 256, 0, stream>>>(Xb, Wqb, bq, bk, bv, nullptr, qh, 2304, 768);
  vtrans_k<<<dim3(64, 24), 256, 0, stream>>>(vh, vth);
  attn_k<<<dim3(32, 24), 512, 157184, stream>>>(qh, kh, vth, am, ctx);
  gemm_bt<2><<<dim3(64, 6), 256, 0, stream>>>(ctx, Wdb, bd, nullptr, nullptr, hid, ln1in, 768, 768);
  ln_k<1><<<2048, 256, 0, stream>>>(ln1in, g1, b1, aob);
  gemm_bt<1><<<dim3(64, 24), 256, 0, stream>>>(aob, Wfb, bf, nullptr, nullptr, nullptr, ffb, 3072, 768);
  gemm_bt<3><<<dim3(64, 6), 256, 0, stream>>>(ffb, Wob, bo, nullptr, nullptr, aob, f2r, 768, 3072);
  ln_k<0><<<2048, 256, 0, stream>>>(f2r, g2, b2, d_out);
}

// Round 3
// 255.501 us; speedup vs baseline: 1.2546x; 1.2546x over previous
//
#include <hip/hip_runtime.h>
#include <cstdint>
#include <cstddef>

#define S_LEN 4096
#define HIDD 768
#define NH 12
#define FFD 3072

typedef float f32x4 __attribute__((ext_vector_type(4)));
typedef short s16x8 __attribute__((ext_vector_type(8)));
typedef short s16x4 __attribute__((ext_vector_type(4)));

__device__ __forceinline__ short f2bf(float f) {
  unsigned u = __float_as_uint(f);
  u += 0x7fffu + ((u >> 16) & 1u);
  return (short)(u >> 16);
}
__device__ __forceinline__ float bf2f(short s) {
  return __uint_as_float(((unsigned)(unsigned short)s) << 16);
}

// async global->LDS, 16B per lane; LDS dest is wave-uniform base + lane*16
__device__ __forceinline__ void gload16(const short* g, short* l) {
  __builtin_amdgcn_global_load_lds(
      (__attribute__((address_space(1))) void*)(void*)const_cast<short*>(g),
      (__attribute__((address_space(3))) void*)l, 16, 0, 0);
}

// ---------------- conversion: f32 -> bf16 (flat, vectorized) ----------------
__global__ void convx_k(const float* __restrict__ x, short* __restrict__ o) {
  size_t i = (size_t)blockIdx.x * 256 + threadIdx.x;
  float4 f = ((const float4*)x)[i];
  s16x4 v;
  v[0] = f2bf(f.x); v[1] = f2bf(f.y); v[2] = f2bf(f.z); v[3] = f2bf(f.w);
  ((s16x4*)o)[i] = v;
}

// ------------- weight transpose + convert: W[R][C] f32 -> Wt[C][R] bf16 -----
__global__ void wtrans_k(const float* __restrict__ Wq, const float* __restrict__ Wk,
                         const float* __restrict__ Wv, const float* __restrict__ Wd,
                         const float* __restrict__ Wf, const float* __restrict__ Wo,
                         short* __restrict__ oq, short* __restrict__ ok_,
                         short* __restrict__ ov, short* __restrict__ od,
                         short* __restrict__ of_, short* __restrict__ oo) {
  __shared__ float tl[64][65];
  int id = blockIdx.x;
  const float* in; short* out; int R, C, tr, tc;
  if (id < 576) {
    int wsel = id / 144; int t = id % 144; tr = t / 12; tc = t % 12; R = 768; C = 768;
    in = wsel == 0 ? Wq : wsel == 1 ? Wk : wsel == 2 ? Wv : Wd;
    out = wsel == 0 ? oq : wsel == 1 ? ok_ : wsel == 2 ? ov : od;
  } else if (id < 1152) {
    int t = id - 576; tr = t / 48; tc = t % 48; R = 768; C = 3072; in = Wf; out = of_;
  } else {
    int t = id - 1152; tr = t / 12; tc = t % 12; R = 3072; C = 768; in = Wo; out = oo;
  }
  int r0 = tr * 64, c0 = tc * 64;
  int tid = threadIdx.x;
  #pragma unroll
  for (int i = 0; i < 16; i++) {
    int idx = i * 256 + tid; int r = idx >> 6, cc = idx & 63;
    tl[r][cc] = in[(size_t)(r0 + r) * C + c0 + cc];
  }
  __syncthreads();
  #pragma unroll
  for (int i = 0; i < 16; i++) {
    int idx = i * 256 + tid; int cc = idx >> 6, rr = idx & 63;
    out[(size_t)(c0 + cc) * R + r0 + rr] = f2bf(tl[rr][cc]);
  }
}

// ---------------- v head-layout transpose: [bh][s][64] -> [bh][64][s] -------
__global__ void vtrans_k(const short* __restrict__ vh, short* __restrict__ vth) {
  __shared__ short tl[64][72];
  int s0 = blockIdx.x * 64; int bh = blockIdx.y;
  int tid = threadIdx.x;
  const short* base = vh + ((size_t)bh << 18);
  #pragma unroll
  for (int i = 0; i < 16; i++) {
    int idx = i * 256 + tid; int r = idx >> 6, cc = idx & 63;
    tl[r][cc] = base[(size_t)(s0 + r) * 64 + cc];
  }
  __syncthreads();
  short* ob = vth + ((size_t)bh << 18);
  #pragma unroll
  for (int i = 0; i < 16; i++) {
    int idx = i * 256 + tid; int dh = idx >> 6, s = idx & 63;
    ob[((size_t)dh << 12) + s0 + s] = tl[s][dh];
  }
}

// ---------------- generic bf16 GEMM: C[M][N] = A[M][K] * Bt[N][K]^T ---------
// m97 structure + T2 both-sides swizzle: linear LDS tile, global_load_lds
// width=16 staging with PRE-SWIZZLED global source (seg ^= lane>>3), and
// XOR-swizzled LDS fragment reads (col ^= (row&7)<<3). BN = 128 or 64.
// EPI 0: fused QKV (N=2304): per-col {q,k,v} select, (acc+bias)*scale,
//        head-split bf16 -> outbase + which*B*S*HID + [((b*NH+h)*S+s)*64+dh]
// EPI 1: exact GELU(acc+bias) -> bf16 row-major
// EPI 2: acc+bias+resid_f32   -> f32 row-major
// EPI 3: acc+bias+resid_bf16  -> f32 row-major
template <int EPI, int BN>
__global__ void __launch_bounds__(256) gemm_bt(
    const short* __restrict__ A, const short* __restrict__ Bt,
    const float* __restrict__ bias, const float* __restrict__ bias1,
    const float* __restrict__ bias2, const void* __restrict__ resid,
    void* __restrict__ out, int N, int K) {
  constexpr int NT = BN / 32;     // per-wave n-tiles (4 or 2)
  __shared__ __align__(16) short As[128 * 64];
  __shared__ __align__(16) short Bs[BN * 64];
  const int tid = threadIdx.x;
  const int lane = tid & 63;
  const int w = tid >> 6;
  const int wr = w >> 1, wc = w & 1;
  const int m0 = blockIdx.x * 128, n0 = blockIdx.y * BN;
  const int lr = lane >> 3;              // row within 8-row chunk
  const int seg = (lane & 7) ^ lr;       // pre-swizzled 16B segment in row
  f32x4 acc[4][NT];
  #pragma unroll
  for (int i = 0; i < 4; i++)
    #pragma unroll
    for (int j = 0; j < NT; j++) { acc[i][j][0] = 0.f; acc[i][j][1] = 0.f; acc[i][j][2] = 0.f; acc[i][j][3] = 0.f; }

  const short* Ab = A + (size_t)(m0 + lr) * K + seg * 8;
  const short* Bb = Bt + (size_t)(n0 + lr) * K + seg * 8;
  for (int k0 = 0; k0 < K; k0 += 64) {
    #pragma unroll
    for (int i = 0; i < 4; i++) {
      const int ca = w * 4 + i;                       // A chunks 0..15
      gload16(Ab + (size_t)(ca * 8) * K + k0, &As[ca * 512]);
    }
    #pragma unroll
    for (int i = 0; i < NT; i++) {
      const int cb = w * NT + i;                      // B chunks 0..BN/8-1
      gload16(Bb + (size_t)(cb * 8) * K + k0, &Bs[cb * 512]);
    }
    __syncthreads();   // drains vmcnt(0) before barrier
    const int kc = (lane >> 4) * 8;
    #pragma unroll
    for (int ks = 0; ks < 2; ks++) {
      const int kb = ks * 32 + kc;
      s16x8 af[4], bfr[NT];
      #pragma unroll
      for (int mt = 0; mt < 4; mt++) {
        const int arow = wr * 64 + mt * 16 + (lane & 15);
        af[mt] = *(const s16x8*)&As[arow * 64 + (kb ^ ((arow & 7) << 3))];
      }
      #pragma unroll
      for (int nt = 0; nt < NT; nt++) {
        const int brow = wc * (BN / 2) + nt * 16 + (lane & 15);
        bfr[nt] = *(const s16x8*)&Bs[brow * 64 + (kb ^ ((brow & 7) << 3))];
      }
      #pragma unroll
      for (int mt = 0; mt < 4; mt++)
        #pragma unroll
        for (int nt = 0; nt < NT; nt++)
          acc[mt][nt] = __builtin_amdgcn_mfma_f32_16x16x32_bf16(af[mt], bfr[nt], acc[mt][nt], 0, 0, 0);
    }
    __syncthreads();
  }
  #pragma unroll
  for (int nt = 0; nt < NT; nt++) {
    const int col = n0 + wc * (BN / 2) + nt * 16 + (lane & 15);
    if (EPI == 0) {
      const int cwhich = col >= 1536 ? 2 : (col >= 768 ? 1 : 0);
      const int cwi = col - cwhich * 768;
      const float* bsel = cwhich == 0 ? bias : (cwhich == 1 ? bias1 : bias2);
      const float bvv = bsel[cwi];
      const float sc = (cwhich == 0) ? 0.125f : 1.f;
      const int hh = cwi >> 6, dh = cwi & 63;
      short* outp = (short*)out + (size_t)cwhich * ((size_t)8192 * 768);
      #pragma unroll
      for (int mt = 0; mt < 4; mt++) {
        #pragma unroll
        for (int r = 0; r < 4; r++) {
          const int row = m0 + wr * 64 + mt * 16 + (lane >> 4) * 4 + r;
          const int b = row >> 12, s = row & 4095;
          outp[((((size_t)b * NH + hh) * S_LEN + s) << 6) + dh] = f2bf((acc[mt][nt][r] + bvv) * sc);
        }
      }
    } else {
      const float bvv = bias[col];
      #pragma unroll
      for (int mt = 0; mt < 4; mt++) {
        #pragma unroll
        for (int r = 0; r < 4; r++) {
          const int row = m0 + wr * 64 + mt * 16 + (lane >> 4) * 4 + r;
          float v = acc[mt][nt][r] + bvv;
          if (EPI == 1) {
            float g = 0.5f * v * (1.f + erff(v * 0.70710678118f));
            ((short*)out)[(size_t)row * N + col] = f2bf(g);
          } else if (EPI == 2) {
            ((float*)out)[(size_t)row * N + col] = v + ((const float*)resid)[(size_t)row * N + col];
          } else {
            ((float*)out)[(size_t)row * N + col] = v + bf2f(((const short*)resid)[(size_t)row * N + col]);
          }
        }
      }
    }
  }
}

// ---------------- banded attention, one block per (chunk, b*h) --------------
// LDS: Kb [384][72] bf16 (phase 1) overlaid by Vt [64][392] (phase 2),
//      dmw [384] f32, Pb 8 waves x [16][392] bf16.   total 157,184 B
__global__ void __launch_bounds__(512, 1) attn_k(
    const short* __restrict__ qh, const short* __restrict__ kh,
    const short* __restrict__ vth, const int* __restrict__ am,
    short* __restrict__ ctx) {
  extern __shared__ char smraw[];
  short* Kb = (short*)smraw;
  float* dmw = (float*)(smraw + 55296);
  short* Pb = (short*)(smraw + 56832);
  const int c = blockIdx.x;
  const int bh = blockIdx.y;
  const int b = bh / NH, hh = bh % NH;
  const int tid = threadIdx.x, lane = tid & 63, w = tid >> 6;
  const int q0 = c * 128, kw0 = q0 - 128;

  // stage K window (clamped; invalid positions masked later)
  for (int ch = tid; ch < 3072; ch += 512) {
    int n = ch >> 3, seg = ch & 7;
    int kp = kw0 + n; kp = kp < 0 ? 0 : (kp > S_LEN - 1 ? S_LEN - 1 : kp);
    *(s16x8*)&Kb[n * 72 + seg * 8] = *(const s16x8*)&kh[(((size_t)bh * S_LEN + kp) << 6) + seg * 8];
  }
  for (int n = tid; n < 384; n += 512) {
    int kp = kw0 + n;
    float d;
    if (kp < 0 || kp >= S_LEN) d = -1e30f;
    else d = (am[b * S_LEN + kp] != 0) ? -10000.f : 0.f;
    dmw[n] = d;
  }
  __syncthreads();

  // Q fragments (direct from global, q pre-scaled by 1/8)
  const short* qrow = qh + ((((size_t)bh * S_LEN) + q0 + w * 16 + (lane & 15)) << 6);
  s16x8 aq0 = *(const s16x8*)&qrow[(lane >> 4) * 8];
  s16x8 aq1 = *(const s16x8*)&qrow[32 + (lane >> 4) * 8];

  f32x4 sacc[24];
  #pragma unroll
  for (int t = 0; t < 24; t++) { sacc[t][0] = 0.f; sacc[t][1] = 0.f; sacc[t][2] = 0.f; sacc[t][3] = 0.f; }
  #pragma unroll
  for (int t = 0; t < 24; t++) {
    const short* kr = &Kb[(t * 16 + (lane & 15)) * 72 + (lane >> 4) * 8];
    s16x8 bk0 = *(const s16x8*)&kr[0];
    s16x8 bk1 = *(const s16x8*)&kr[32];
    sacc[t] = __builtin_amdgcn_mfma_f32_16x16x32_bf16(aq0, bk0, sacc[t], 0, 0, 0);
    sacc[t] = __builtin_amdgcn_mfma_f32_16x16x32_bf16(aq1, bk1, sacc[t], 0, 0, 0);
  }
  // masks (band + position/attention mask)
  const int mbase = w * 16 + (lane >> 4) * 4;
  #pragma unroll
  for (int t = 0; t < 24; t++) {
    int n = t * 16 + (lane & 15);
    float d = dmw[n];
    #pragma unroll
    for (int r = 0; r < 4; r++) {
      int j = n - (mbase + r);
      float sv = sacc[t][r] + d;
      if (j < 0 || j > 256) sv = -1e30f;
      sacc[t][r] = sv;
    }
  }
  // softmax (rows spread over 16-lane groups) + P -> LDS bf16
  short* Pw = Pb + w * 16 * 392;
  #pragma unroll
  for (int r = 0; r < 4; r++) {
    float mx = -3e38f;
    #pragma unroll
    for (int t = 0; t < 24; t++) mx = fmaxf(mx, sacc[t][r]);
    #pragma unroll
    for (int d = 1; d < 16; d <<= 1) mx = fmaxf(mx, __shfl_xor(mx, d));
    float sum = 0.f;
    #pragma unroll
    for (int t = 0; t < 24; t++) { float p = __expf(sacc[t][r] - mx); sacc[t][r] = p; sum += p; }
    #pragma unroll
    for (int d = 1; d < 16; d <<= 1) sum += __shfl_xor(sum, d);
    float inv = 1.f / sum;
    #pragma unroll
    for (int t = 0; t < 24; t++)
      Pw[((lane >> 4) * 4 + r) * 392 + t * 16 + (lane & 15)] = f2bf(sacc[t][r] * inv);
  }
  __syncthreads();  // everyone done reading Kb

  // stage Vt (overlay Kb): Vt[dh][n] = v^T, rows contiguous in n
  short* Vt = (short*)smraw;
  for (int ch = tid; ch < 3072; ch += 512) {
    int dh = ch / 48, seg = ch % 48;
    int n0 = seg * 8, kp0 = kw0 + n0;
    const short* vr = vth + (((size_t)bh * 64 + dh) << 12);
    s16x8 vv;
    if (kp0 >= 0 && kp0 + 7 < S_LEN) {
      vv = *(const s16x8*)&vr[kp0];
    } else {
      #pragma unroll
      for (int e = 0; e < 8; e++) {
        int kp = kp0 + e; kp = kp < 0 ? 0 : (kp > S_LEN - 1 ? S_LEN - 1 : kp);
        vv[e] = vr[kp];
      }
    }
    *(s16x8*)&Vt[dh * 392 + n0] = vv;
  }
  __syncthreads();

  // PV: C2[16][64] per wave
  f32x4 oacc[4];
  #pragma unroll
  for (int i = 0; i < 4; i++) { oacc[i][0] = 0.f; oacc[i][1] = 0.f; oacc[i][2] = 0.f; oacc[i][3] = 0.f; }
  #pragma unroll
  for (int ksp = 0; ksp < 12; ksp++) {
    s16x8 pa = *(const s16x8*)&Pw[(lane & 15) * 392 + ksp * 32 + (lane >> 4) * 8];
    #pragma unroll
    for (int ct = 0; ct < 4; ct++) {
      s16x8 vb = *(const s16x8*)&Vt[(ct * 16 + (lane & 15)) * 392 + ksp * 32 + (lane >> 4) * 8];
      oacc[ct] = __builtin_amdgcn_mfma_f32_16x16x32_bf16(pa, vb, oacc[ct], 0, 0, 0);
    }
  }
  // write ctx as [B][S][H*64] bf16
  #pragma unroll
  for (int ct = 0; ct < 4; ct++) {
    #pragma unroll
    for (int r = 0; r < 4; r++) {
      int srow = q0 + w * 16 + (lane >> 4) * 4 + r;
      int col = hh * 64 + ct * 16 + (lane & 15);
      ctx[((size_t)b * S_LEN + srow) * HIDD + col] = f2bf(oacc[ct][r]);
    }
  }
}

// ---------------- LayerNorm, one wave per row (HID=768) ---------------------
template <int OUTBF>
__global__ void ln_k(const float* __restrict__ in, const float* __restrict__ g,
                     const float* __restrict__ bb, void* __restrict__ out) {
  int row = blockIdx.x * 4 + (threadIdx.x >> 6);
  int lane = threadIdx.x & 63;
  const float4* x = (const float4*)(in + (size_t)row * HIDD);
  float4 v0 = x[lane], v1 = x[lane + 64], v2 = x[lane + 128];
  float s = v0.x + v0.y + v0.z + v0.w + v1.x + v1.y + v1.z + v1.w + v2.x + v2.y + v2.z + v2.w;
  float ss = v0.x * v0.x + v0.y * v0.y + v0.z * v0.z + v0.w * v0.w
           + v1.x * v1.x + v1.y * v1.y + v1.z * v1.z + v1.w * v1.w
           + v2.x * v2.x + v2.y * v2.y + v2.z * v2.z + v2.w * v2.w;
  #pragma unroll
  for (int d = 1; d < 64; d <<= 1) { s += __shfl_xor(s, d); ss += __shfl_xor(ss, d); }
  float mean = s * (1.f / 768.f);
  float var = ss * (1.f / 768.f) - mean * mean;
  float rs = rsqrtf(var + 1e-12f);
  const float4* gp = (const float4*)g;
  const float4* bp = (const float4*)bb;
  #pragma unroll
  for (int seg = 0; seg < 3; seg++) {
    int idx = lane + seg * 64;
    float4 vv = seg == 0 ? v0 : seg == 1 ? v1 : v2;
    float4 gg = gp[idx], b4 = bp[idx];
    float o0 = (vv.x - mean) * rs * gg.x + b4.x;
    float o1 = (vv.y - mean) * rs * gg.y + b4.y;
    float o2 = (vv.z - mean) * rs * gg.z + b4.z;
    float o3 = (vv.w - mean) * rs * gg.w + b4.w;
    if (OUTBF) {
      s16x4 o; o[0] = f2bf(o0); o[1] = f2bf(o1); o[2] = f2bf(o2); o[3] = f2bf(o3);
      ((s16x4*)out)[(size_t)row * 192 + idx] = o;
    } else {
      float4 o; o.x = o0; o.y = o1; o.z = o2; o.w = o3;
      ((float4*)out)[(size_t)row * 192 + idx] = o;
    }
  }
}

extern "C" void kernel_launch(void* const* d_in, const int* in_sizes, int n_in,
                              void* d_out, int out_size, void* d_ws, size_t ws_size,
                              hipStream_t stream) {
  const float* hid = (const float*)d_in[0];
  const int* am = (const int*)d_in[1];
  const float* Wq = (const float*)d_in[2];  const float* bq = (const float*)d_in[3];
  const float* Wk = (const float*)d_in[4];  const float* bk = (const float*)d_in[5];
  const float* Wv = (const float*)d_in[6];  const float* bv = (const float*)d_in[7];
  const float* Wd = (const float*)d_in[8];  const float* bd = (const float*)d_in[9];
  const float* g1 = (const float*)d_in[10]; const float* b1 = (const float*)d_in[11];
  const float* Wf = (const float*)d_in[12]; const float* bf = (const float*)d_in[13];
  const float* Wo = (const float*)d_in[14]; const float* bo = (const float*)d_in[15];
  const float* g2 = (const float*)d_in[16]; const float* b2 = (const float*)d_in[17];

  char* ws = (char*)d_ws;
  size_t off = 0;
  auto alloc = [&](size_t bytes) { char* p = ws + off; off += (bytes + 255) & ~(size_t)255; return p; };
  short* Xb   = (short*)alloc((size_t)8192 * 768 * 2);
  // Wqb/Wkb/Wvb contiguous (fused QKV reads them as one [2304][768] Bt)
  short* Wqb  = (short*)alloc((size_t)768 * 768 * 2);
  short* Wkb  = (short*)alloc((size_t)768 * 768 * 2);
  short* Wvb  = (short*)alloc((size_t)768 * 768 * 2);
  short* Wdb  = (short*)alloc((size_t)768 * 768 * 2);
  short* Wfb  = (short*)alloc((size_t)3072 * 768 * 2);
  short* Wob  = (short*)alloc((size_t)768 * 3072 * 2);
  // qh/kh/vh contiguous (fused QKV epilogue indexes qh + which*8192*768)
  short* qh   = (short*)alloc((size_t)8192 * 768 * 2);
  short* kh   = (short*)alloc((size_t)8192 * 768 * 2);
  short* vh   = (short*)alloc((size_t)8192 * 768 * 2);
  short* vth  = (short*)alloc((size_t)8192 * 768 * 2);
  short* ctx  = (short*)alloc((size_t)8192 * 768 * 2);
  short* aob  = (short*)alloc((size_t)8192 * 768 * 2);   // attn_out bf16
  short* ffb  = (short*)alloc((size_t)8192 * 3072 * 2);
  float* f2r  = (float*)alloc((size_t)8192 * 768 * 4);   // ff2 + resid f32
  float* ln1in = (float*)d_out;                          // d_out as f32 scratch
  (void)vh; (void)kh;

  hipFuncSetAttribute(reinterpret_cast<const void*>(attn_k),
                      hipFuncAttributeMaxDynamicSharedMemorySize, 157184);

  convx_k<<<6144, 256, 0, stream>>>(hid, Xb);
  wtrans_k<<<1728, 256, 0, stream>>>(Wq, Wk, Wv, Wd, Wf, Wo, Wqb, Wkb, Wvb, Wdb, Wfb, Wob);

  // fused QKV: C[8192][2304] = Xb * [Wqb;Wkb;Wvb]^T, head-split epilogue
  gemm_bt<0, 128><<<dim3(64, 18), 256, 0, stream>>>(Xb, Wqb, bq, bk, bv, nullptr, qh, 2304, 768);
  vtrans_k<<<dim3(64, 24), 256, 0, stream>>>(vh, vth);
  attn_k<<<dim3(32, 24), 512, 157184, stream>>>(qh, kh, vth, am, ctx);
  gemm_bt<2, 64><<<dim3(64, 12), 256, 0, stream>>>(ctx, Wdb, bd, nullptr, nullptr, hid, ln1in, 768, 768);
  ln_k<1><<<2048, 256, 0, stream>>>(ln1in, g1, b1, aob);
  gemm_bt<1, 128><<<dim3(64, 24), 256, 0, stream>>>(aob, Wfb, bf, nullptr, nullptr, nullptr, ffb, 3072, 768);
  gemm_bt<3, 64><<<dim3(64, 12), 256, 0, stream>>>(ffb, Wob, bo, nullptr, nullptr, aob, f2r, 768, 3072);
  ln_k<0><<<2048, 256, 0, stream>>>(f2r, g2, b2, d_out);
}